// Round 4
// baseline (152.415 us; speedup 1.0000x reference)
//
#include <hip/hip_runtime.h>
#include <hip/hip_bf16.h>
#include <math.h>
#include <stdint.h>

// ---------------------------------------------------------------------------
// MultiSimilarityLoss on MI355X (gfx950).
//   x: [B=4096, D=1024] fp32 (L2-normalized), labels: [B] int32 -> scalar loss
//
// R4 pipeline (no full sim materialization, no mirror writes):
//   K1 cvt:      x fp32 -> bf16
//   K2 gemm+mine: triangle-packed 528 blocks (linear->triangle unrank, no dead
//                blocks). Computes upper 128x128 tiles of sim=X@X^T, stores
//                them (34.6 MB, coalesced), and mines per-row AND per-column
//                min_pos / max_neg from the accumulators (the transpose lives
//                in the same registers) via keyed uint atomicMin/Max.
//   K3 exploss:  streams upper tiles (L2-hot), one exp per element,
//                contributes to row-side and col-side psum/nsum arrays.
//   K4 final:    per-row loss + reduce -> out[0].
// R3 post-mortem: dead blocks wrecked balance (VALUBusy 4.8%) and the mirror
// scatter stalled the store pipe. Both are eliminated structurally here.
// ---------------------------------------------------------------------------

#define THRESH    0.5f
#define MARGIN    0.1f
#define SCALE_POS 2.0f
#define SCALE_NEG 40.0f
#define POS_CAP   (1.0f - 1e-5f)

typedef __bf16 bf16x8 __attribute__((ext_vector_type(8)));
typedef float  f32x4  __attribute__((ext_vector_type(4)));

// ---- fp32 -> bf16 (RNE) ----------------------------------------------------
__device__ __forceinline__ uint16_t f2bf(float f) {
  union { float f; uint32_t u; } v; v.f = f;
  uint32_t u = v.u;
  u += 0x7FFFu + ((u >> 16) & 1u);
  return (uint16_t)(u >> 16);
}

__global__ __launch_bounds__(256) void cvt_bf16_kernel(
    const float* __restrict__ x, uint16_t* __restrict__ y, int n) {
  int i = (blockIdx.x * 256 + threadIdx.x) * 4;
  if (i + 3 < n) {
    float4 v = *(const float4*)(x + i);
    ushort4 o;
    o.x = f2bf(v.x); o.y = f2bf(v.y); o.z = f2bf(v.z); o.w = f2bf(v.w);
    *(ushort4*)(y + i) = o;
  }
}

// ---- monotone float <-> uint key (for atomicMin/Max on floats) -------------
// f1 < f2  <=>  fkey(f1) < fkey(f2). Sentinels: 0xFFFFFFFF decodes to NaN
// (acts as "+inf absent": s+M > NaN == false); 0x0 decodes to NaN too
// ("-inf absent": s-M < NaN == false). Finite sims never produce either key.
__device__ __forceinline__ unsigned fkey(float f) {
  unsigned u = __float_as_uint(f);
  return (u & 0x80000000u) ? ~u : (u | 0x80000000u);
}
__device__ __forceinline__ float funkey(unsigned k) {
  unsigned u = (k & 0x80000000u) ? (k & 0x7FFFFFFFu) : ~k;
  return __uint_as_float(u);
}

// ---- async global->LDS staging (16B / lane) --------------------------------
#if defined(__has_builtin)
#if __has_builtin(__builtin_amdgcn_global_load_lds)
#define HAVE_GLL 1
#endif
#endif

__device__ __forceinline__ void stage16(const uint16_t* g, uint16_t* lds_wave_base, int lane) {
#ifdef HAVE_GLL
  __builtin_amdgcn_global_load_lds(
      (const __attribute__((address_space(1))) void*)g,
      (__attribute__((address_space(3))) void*)lds_wave_base, 16, 0, 0);
#else
  *(uint4*)(lds_wave_base + lane * 8) = *(const uint4*)g;
#endif
}

// ---- K2: triangle GEMM + min/max mining ------------------------------------
__global__ __launch_bounds__(256) void simgemm_mine_kernel(
    const uint16_t* __restrict__ X, const int* __restrict__ labels,
    float* __restrict__ C, unsigned* __restrict__ minKey,
    unsigned* __restrict__ maxKey, int B, int D, int NT) {
  __shared__ __align__(16) uint16_t sA[128 * 32];
  __shared__ __align__(16) uint16_t sB[128 * 32];
  __shared__ int rowLab[128];
  __shared__ int colLab[128];

  // linear -> (bi, bj) with bi <= bj; row bi holds NT-bi tiles
  int rem = blockIdx.x;
  int bi = 0;
  while (rem >= NT - bi) { rem -= NT - bi; ++bi; }
  const int bj = bi + rem;
  const bool diag = (bi == bj);

  const int tid  = threadIdx.x;
  const int wave = tid >> 6;
  const int lane = tid & 63;
  const int waveM = wave >> 1, waveN = wave & 1;
  const int bm = bi * 128;
  const int bn = bj * 128;

  if (tid < 128) rowLab[tid] = labels[bm + tid];
  else           colLab[tid - 128] = labels[bn + tid - 128];

  const int ch0 = tid;
  const int ch1 = tid + 256;
  const int r0 = ch0 >> 2, c0 = (ch0 & 3) * 8;
  const int r1 = ch1 >> 2, c1 = (ch1 & 3) * 8;

  const uint16_t* gA = X + (size_t)bm * D;
  const uint16_t* gB = X + (size_t)bn * D;

  uint16_t* lA0 = sA + wave * 512;
  uint16_t* lA1 = sA + 2048 + wave * 512;
  uint16_t* lB0 = sB + wave * 512;
  uint16_t* lB1 = sB + 2048 + wave * 512;

  const int fr = lane & 15;
  const int fq = lane >> 4;
  const int aoff = (waveM * 64 + fr) * 32 + fq * 8;
  const int boff = (waveN * 64 + fr) * 32 + fq * 8;

  const uint16_t* sBsrc = diag ? sA : sB;

  f32x4 acc[4][4] = {};

  for (int k0 = 0; k0 < D; k0 += 32) {
    stage16(gA + (size_t)r0 * D + k0 + c0, lA0, lane);
    stage16(gA + (size_t)r1 * D + k0 + c1, lA1, lane);
    if (!diag) {
      stage16(gB + (size_t)r0 * D + k0 + c0, lB0, lane);
      stage16(gB + (size_t)r1 * D + k0 + c1, lB1, lane);
    }
    __syncthreads();

    bf16x8 af[4], bfv[4];
#pragma unroll
    for (int t = 0; t < 4; ++t) af[t]  = *(const bf16x8*)(sA + aoff + t * 512);
#pragma unroll
    for (int t = 0; t < 4; ++t) bfv[t] = *(const bf16x8*)(sBsrc + boff + t * 512);

#pragma unroll
    for (int mt = 0; mt < 4; ++mt)
#pragma unroll
      for (int nt = 0; nt < 4; ++nt)
        acc[mt][nt] = __builtin_amdgcn_mfma_f32_16x16x32_bf16(
            af[mt], bfv[nt], acc[mt][nt], 0, 0, 0);
    __syncthreads();
  }

  // ---- store upper tile (coalesced 64B segments) ----
#pragma unroll
  for (int mt = 0; mt < 4; ++mt)
#pragma unroll
    for (int nt = 0; nt < 4; ++nt) {
      const int col = bn + waveN * 64 + nt * 16 + fr;
#pragma unroll
      for (int r = 0; r < 4; ++r) {
        const int row = bm + waveM * 64 + mt * 16 + fq * 4 + r;
        C[(size_t)row * B + col] = acc[mt][nt][r];
      }
    }

  // ---- mine per-row (bm-side) and per-col (bn-side) min_pos / max_neg ----
  int labC[4]; float cMin[4], cMax[4];
#pragma unroll
  for (int nt = 0; nt < 4; ++nt) {
    labC[nt] = colLab[waveN * 64 + nt * 16 + fr];
    cMin[nt] = 1e30f; cMax[nt] = -1e30f;
  }

#pragma unroll
  for (int mt = 0; mt < 4; ++mt) {
    float rMin[4], rMax[4]; int labR[4];
#pragma unroll
    for (int r = 0; r < 4; ++r) {
      labR[r] = rowLab[waveM * 64 + mt * 16 + fq * 4 + r];
      rMin[r] = 1e30f; rMax[r] = -1e30f;
    }
#pragma unroll
    for (int nt = 0; nt < 4; ++nt) {
      const int cl = waveN * 64 + nt * 16 + fr;
#pragma unroll
      for (int r = 0; r < 4; ++r) {
        const int rl = waveM * 64 + mt * 16 + fq * 4 + r;
        const float s = acc[mt][nt][r];
        if (labR[r] == labC[nt]) {
          if (!(diag && rl == cl) && s < POS_CAP) {
            rMin[r] = fminf(rMin[r], s);
            cMin[nt] = fminf(cMin[nt], s);
          }
        } else {
          rMax[r] = fmaxf(rMax[r], s);
          cMax[nt] = fmaxf(cMax[nt], s);
        }
      }
    }
    // reduce across the 16 fr-lanes of each quad
#pragma unroll
    for (int m = 1; m < 16; m <<= 1)
#pragma unroll
      for (int r = 0; r < 4; ++r) {
        rMin[r] = fminf(rMin[r], __shfl_xor(rMin[r], m, 64));
        rMax[r] = fmaxf(rMax[r], __shfl_xor(rMax[r], m, 64));
      }
    if (fr == 0) {
#pragma unroll
      for (int r = 0; r < 4; ++r) {
        const int row = bm + waveM * 64 + mt * 16 + fq * 4 + r;
        if (rMin[r] < 2.f)  atomicMin(&minKey[row], fkey(rMin[r]));
        if (rMax[r] > -2.f) atomicMax(&maxKey[row], fkey(rMax[r]));
      }
    }
  }

  if (!diag) {  // diag tile already saw both orders on the row side
#pragma unroll
    for (int m = 16; m < 64; m <<= 1)
#pragma unroll
      for (int nt = 0; nt < 4; ++nt) {
        cMin[nt] = fminf(cMin[nt], __shfl_xor(cMin[nt], m, 64));
        cMax[nt] = fmaxf(cMax[nt], __shfl_xor(cMax[nt], m, 64));
      }
    if (lane < 16) {
#pragma unroll
      for (int nt = 0; nt < 4; ++nt) {
        const int col = bn + waveN * 64 + nt * 16 + fr;
        if (cMin[nt] < 2.f)  atomicMin(&minKey[col], fkey(cMin[nt]));
        if (cMax[nt] > -2.f) atomicMax(&maxKey[col], fkey(cMax[nt]));
      }
    }
  }
}

// ---- K3: stream upper tiles, accumulate mined exp-sums both sides ----------
// grid = NTILES*4; block covers a 32x128 slice of one upper tile.
// thread: rowg = tid>>5 (8 rows, 4 iters), cols (tid&31)*4 .. +3 (float4).
__global__ __launch_bounds__(256) void exploss_kernel(
    const float* __restrict__ C, const int* __restrict__ labels,
    const unsigned* __restrict__ minKey, const unsigned* __restrict__ maxKey,
    float* __restrict__ psum, float* __restrict__ nsum, int B, int NT) {
  __shared__ int   rLab[32];
  __shared__ float rMinp[32], rMaxn[32];
  __shared__ int   cLab[128];
  __shared__ float cMinp[128], cMaxn[128];
  __shared__ float pCarr[128], nCarr[128];

  int rem = blockIdx.x >> 2;
  const int split = blockIdx.x & 3;
  int bi = 0;
  while (rem >= NT - bi) { rem -= NT - bi; ++bi; }
  const int bj = bi + rem;
  const bool diag = (bi == bj);
  const int bm = bi * 128, bn = bj * 128;
  const int rbase = split * 32;

  const int tid = threadIdx.x;
  if (tid < 32) {
    const int row = bm + rbase + tid;
    rLab[tid]  = labels[row];
    rMinp[tid] = funkey(minKey[row]);
    rMaxn[tid] = funkey(maxKey[row]);
  } else if (tid < 160) {
    const int col = bn + (tid - 32);
    cLab[tid - 32]  = labels[col];
    cMinp[tid - 32] = funkey(minKey[col]);
    cMaxn[tid - 32] = funkey(maxKey[col]);
  }
  if (tid < 128) { pCarr[tid] = 0.f; nCarr[tid] = 0.f; }
  __syncthreads();

  const int rowg = tid >> 5;
  const int c0   = (tid & 31) * 4;
  int labC[4]; float mpC[4], mnC[4];
#pragma unroll
  for (int q = 0; q < 4; ++q) {
    labC[q] = cLab[c0 + q]; mpC[q] = cMinp[c0 + q]; mnC[q] = cMaxn[c0 + q];
  }
  float pCa[4] = {0.f, 0.f, 0.f, 0.f}, nCa[4] = {0.f, 0.f, 0.f, 0.f};

  for (int it = 0; it < 4; ++it) {
    const int rr = rowg + it * 8;           // 0..31 within slice
    const int rl = rbase + rr;              // 0..127 within tile
    const float4 v = *(const float4*)(C + (size_t)(bm + rl) * B + bn + c0);
    const float sq[4] = {v.x, v.y, v.z, v.w};
    const int   lr  = rLab[rr];
    const float rmn = rMaxn[rr];
    const float rmp = rMinp[rr];
    float pR = 0.f, nR = 0.f;
#pragma unroll
    for (int q = 0; q < 4; ++q) {
      const float s = sq[q];
      if (lr == labC[q]) {
        if (!(diag && rl == c0 + q) && s < POS_CAP) {
          const float e = __expf(-SCALE_POS * (s - THRESH));
          if (s - MARGIN < rmn)    pR += e;       // row side keep
          if (s - MARGIN < mnC[q]) pCa[q] += e;   // col (mirror) side keep
        }
      } else {
        const float e = __expf(SCALE_NEG * (s - THRESH));
        if (s + MARGIN > rmp)    nR += e;
        if (s + MARGIN > mpC[q]) nCa[q] += e;
      }
    }
    // reduce row-side across the 32 threads sharing this row
#pragma unroll
    for (int m = 1; m < 32; m <<= 1) {
      pR += __shfl_xor(pR, m, 64);
      nR += __shfl_xor(nR, m, 64);
    }
    if ((tid & 31) == 0) {
      atomicAdd(&psum[bm + rl], pR);
      atomicAdd(&nsum[bm + rl], nR);
    }
  }

  if (!diag) {  // col side would double-count on diag tiles
#pragma unroll
    for (int q = 0; q < 4; ++q) {
      atomicAdd(&pCarr[c0 + q], pCa[q]);
      atomicAdd(&nCarr[c0 + q], nCa[q]);
    }
    __syncthreads();
    if (tid < 128) {
      if (pCarr[tid] != 0.f) atomicAdd(&psum[bn + tid], pCarr[tid]);
      if (nCarr[tid] != 0.f) atomicAdd(&nsum[bn + tid], nCarr[tid]);
    }
  }
}

// ---- K4: per-row loss + total ----------------------------------------------
__global__ __launch_bounds__(1024) void final_kernel(
    const unsigned* __restrict__ minKey, const unsigned* __restrict__ maxKey,
    const float* __restrict__ psum, const float* __restrict__ nsum,
    float* __restrict__ out, int B) {
  __shared__ float red[16];
  const int tid = threadIdx.x;
  float acc = 0.f;
  for (int i = tid; i < B; i += 1024) {
    const unsigned mk = minKey[i], xk = maxKey[i];
    const float p = psum[i], n = nsum[i];
    if (mk != 0xFFFFFFFFu && xk != 0u && p > 0.f && n > 0.f)
      acc += log1pf(p) * (1.0f / SCALE_POS) + log1pf(n) * (1.0f / SCALE_NEG);
  }
#pragma unroll
  for (int m = 32; m > 0; m >>= 1) acc += __shfl_xor(acc, m, 64);
  if ((tid & 63) == 0) red[tid >> 6] = acc;
  __syncthreads();
  if (tid == 0) {
    float t = 0.f;
#pragma unroll
    for (int w = 0; w < 16; ++w) t += red[w];
    out[0] = t / (float)B;
  }
}

// ---------------------------------------------------------------------------
extern "C" void kernel_launch(void* const* d_in, const int* in_sizes, int n_in,
                              void* d_out, int out_size, void* d_ws, size_t ws_size,
                              hipStream_t stream) {
  const float* x      = (const float*)d_in[0];
  const int*   labels = (const int*)d_in[1];
  float*       out    = (float*)d_out;

  const int B = in_sizes[1];           // 4096
  const int D = in_sizes[0] / B;       // 1024
  const int NT = B / 128;              // 32
  const int NTILES = NT * (NT + 1) / 2;  // 528

  uint16_t* xbf = (uint16_t*)d_ws;
  size_t xbytes = (((size_t)B * D * 2) + 255) & ~(size_t)255;
  float* sim = (float*)((char*)d_ws + xbytes);
  size_t simbytes = (size_t)B * B * 4;
  unsigned* minKey = (unsigned*)((char*)d_ws + xbytes + simbytes);
  unsigned* maxKey = minKey + B;
  float* psumA = (float*)(maxKey + B);
  float* nsumA = psumA + B;

  hipMemsetAsync(minKey, 0xFF, (size_t)B * 4, stream);
  hipMemsetAsync(maxKey, 0x00, (size_t)B * 12, stream);  // maxKey+psum+nsum

  const int n = B * D;
  cvt_bf16_kernel<<<n / 1024, 256, 0, stream>>>(x, xbf, n);

  simgemm_mine_kernel<<<NTILES, 256, 0, stream>>>(xbf, labels, sim, minKey, maxKey, B, D, NT);
  exploss_kernel<<<NTILES * 4, 256, 0, stream>>>(sim, labels, minKey, maxKey, psumA, nsumA, B, NT);
  final_kernel<<<1, 1024, 0, stream>>>(minKey, maxKey, psumA, nsumA, out, B);
}

// Round 6
// 151.159 us; speedup vs baseline: 1.0083x; 1.0083x over previous
//
#include <hip/hip_runtime.h>
#include <hip/hip_bf16.h>
#include <hip/hip_cooperative_groups.h>
#include <math.h>
#include <stdint.h>

namespace cg = cooperative_groups;

// ---------------------------------------------------------------------------
// MultiSimilarityLoss on MI355X (gfx950).
//   x: [B=4096, D=1024] fp32 (L2-normalized), labels: [B] int32 -> scalar loss
//
// R6: fused cooperative pipeline (sim never materialized) with the R5 launch
// failure fixed:
//   - R5 failed because keeping acc live across grid.sync() pushed VGPR>128
//     -> 2 blocks/CU -> coop capacity 512 < 528 blocks -> launch rejected.
//   - Fix: __launch_bounds__(256,3) caps VGPR ~170 -> 3 blocks/CU -> 768 cap.
//   - Safety: host occupancy query picks fused path only if it truly fits;
//     otherwise falls back to the R4 materializing path (known-correct).
// ---------------------------------------------------------------------------

#define THRESH    0.5f
#define MARGIN    0.1f
#define SCALE_POS 2.0f
#define SCALE_NEG 40.0f
#define POS_CAP   (1.0f - 1e-5f)

typedef __bf16 bf16x8 __attribute__((ext_vector_type(8)));
typedef float  f32x4  __attribute__((ext_vector_type(4)));

// ---- fp32 -> bf16 (RNE) ----------------------------------------------------
__device__ __forceinline__ uint16_t f2bf(float f) {
  union { float f; uint32_t u; } v; v.f = f;
  uint32_t u = v.u;
  u += 0x7FFFu + ((u >> 16) & 1u);
  return (uint16_t)(u >> 16);
}

__global__ __launch_bounds__(256) void cvt_bf16_kernel(
    const float* __restrict__ x, uint16_t* __restrict__ y, int n) {
  int i = (blockIdx.x * 256 + threadIdx.x) * 4;
  if (i + 3 < n) {
    float4 v = *(const float4*)(x + i);
    ushort4 o;
    o.x = f2bf(v.x); o.y = f2bf(v.y); o.z = f2bf(v.z); o.w = f2bf(v.w);
    *(ushort4*)(y + i) = o;
  }
}

// ---- monotone float <-> uint key (atomicMin/Max on floats) -----------------
// Sentinels: minKey=0xFFFFFFFF and maxKey=0x0 decode to NaN -> comparisons
// against "empty" extrema are false (matches +/-inf reference semantics).
__device__ __forceinline__ unsigned fkey(float f) {
  unsigned u = __float_as_uint(f);
  return (u & 0x80000000u) ? ~u : (u | 0x80000000u);
}
__device__ __forceinline__ float funkey(unsigned k) {
  unsigned u = (k & 0x80000000u) ? (k & 0x7FFFFFFFu) : ~k;
  return __uint_as_float(u);
}

// ---- async global->LDS staging (16B / lane) --------------------------------
#if defined(__has_builtin)
#if __has_builtin(__builtin_amdgcn_global_load_lds)
#define HAVE_GLL 1
#endif
#endif

__device__ __forceinline__ void stage16(const uint16_t* g, uint16_t* lds_wave_base, int lane) {
#ifdef HAVE_GLL
  __builtin_amdgcn_global_load_lds(
      (const __attribute__((address_space(1))) void*)g,
      (__attribute__((address_space(3))) void*)lds_wave_base, 16, 0, 0);
#else
  *(uint4*)(lds_wave_base + lane * 8) = *(const uint4*)g;
#endif
}

// ===========================================================================
// Fused cooperative kernel: triangle GEMM + mine + grid.sync + exp-loss
// ===========================================================================
__global__ __launch_bounds__(256, 3) void fused_kernel(
    const uint16_t* __restrict__ X, const int* __restrict__ labels,
    unsigned* __restrict__ minKey, unsigned* __restrict__ maxKey,
    float* __restrict__ psum, float* __restrict__ nsum,
    int B, int D, int NT) {
  __shared__ __align__(16) uint16_t sA[128 * 32];
  __shared__ __align__(16) uint16_t sB[128 * 32];
  __shared__ int rowLab[128], colLab[128];
  __shared__ float rMinp[128], rMaxn[128], cMinp[128], cMaxn[128];

  int rem = blockIdx.x;
  int bi = 0;
  while (rem >= NT - bi) { rem -= NT - bi; ++bi; }
  const int bj = bi + rem;
  const bool diag = (bi == bj);

  const int tid  = threadIdx.x;
  const int wave = tid >> 6;
  const int lane = tid & 63;
  const int waveM = wave >> 1, waveN = wave & 1;
  const int bm = bi * 128;
  const int bn = bj * 128;

  if (tid < 128) rowLab[tid] = labels[bm + tid];
  else           colLab[tid - 128] = labels[bn + tid - 128];

  const int r0 = tid >> 2,         c0 = (tid & 3) * 8;
  const int r1 = (tid + 256) >> 2, c1 = (tid & 3) * 8;

  const uint16_t* gA = X + (size_t)bm * D;
  const uint16_t* gB = X + (size_t)bn * D;

  uint16_t* lA0 = sA + wave * 512;
  uint16_t* lA1 = sA + 2048 + wave * 512;
  uint16_t* lB0 = sB + wave * 512;
  uint16_t* lB1 = sB + 2048 + wave * 512;

  const int fr = lane & 15;
  const int fq = lane >> 4;
  const int aoff = (waveM * 64 + fr) * 32 + fq * 8;
  const int boff = (waveN * 64 + fr) * 32 + fq * 8;

  const uint16_t* sBsrc = diag ? sA : sB;

  f32x4 acc[4][4] = {};

  for (int k0 = 0; k0 < D; k0 += 32) {
    stage16(gA + (size_t)r0 * D + k0 + c0, lA0, lane);
    stage16(gA + (size_t)r1 * D + k0 + c1, lA1, lane);
    if (!diag) {
      stage16(gB + (size_t)r0 * D + k0 + c0, lB0, lane);
      stage16(gB + (size_t)r1 * D + k0 + c1, lB1, lane);
    }
    __syncthreads();

    bf16x8 af[4], bfv[4];
#pragma unroll
    for (int t = 0; t < 4; ++t) af[t]  = *(const bf16x8*)(sA + aoff + t * 512);
#pragma unroll
    for (int t = 0; t < 4; ++t) bfv[t] = *(const bf16x8*)(sBsrc + boff + t * 512);

#pragma unroll
    for (int mt = 0; mt < 4; ++mt)
#pragma unroll
      for (int nt = 0; nt < 4; ++nt)
        acc[mt][nt] = __builtin_amdgcn_mfma_f32_16x16x32_bf16(
            af[mt], bfv[nt], acc[mt][nt], 0, 0, 0);
    __syncthreads();
  }

  // ---- phase 1: mine per-row + per-col min_pos / max_neg ----
  int labC[4];
#pragma unroll
  for (int nt = 0; nt < 4; ++nt) labC[nt] = colLab[waveN * 64 + nt * 16 + fr];

  {
    float cMin[4], cMax[4];
#pragma unroll
    for (int nt = 0; nt < 4; ++nt) { cMin[nt] = 1e30f; cMax[nt] = -1e30f; }

#pragma unroll
    for (int mt = 0; mt < 4; ++mt) {
      float rMin[4], rMax[4]; int labR[4];
#pragma unroll
      for (int r = 0; r < 4; ++r) {
        labR[r] = rowLab[waveM * 64 + mt * 16 + fq * 4 + r];
        rMin[r] = 1e30f; rMax[r] = -1e30f;
      }
#pragma unroll
      for (int nt = 0; nt < 4; ++nt) {
        const int cl = waveN * 64 + nt * 16 + fr;
#pragma unroll
        for (int r = 0; r < 4; ++r) {
          const int rl = waveM * 64 + mt * 16 + fq * 4 + r;
          const float s = acc[mt][nt][r];
          if (labR[r] == labC[nt]) {
            if (!(diag && rl == cl) && s < POS_CAP) {
              rMin[r] = fminf(rMin[r], s);
              cMin[nt] = fminf(cMin[nt], s);
            }
          } else {
            rMax[r] = fmaxf(rMax[r], s);
            cMax[nt] = fmaxf(cMax[nt], s);
          }
        }
      }
#pragma unroll
      for (int m = 1; m < 16; m <<= 1)
#pragma unroll
        for (int r = 0; r < 4; ++r) {
          rMin[r] = fminf(rMin[r], __shfl_xor(rMin[r], m, 64));
          rMax[r] = fmaxf(rMax[r], __shfl_xor(rMax[r], m, 64));
        }
      if (fr == 0) {
#pragma unroll
        for (int r = 0; r < 4; ++r) {
          const int row = bm + waveM * 64 + mt * 16 + fq * 4 + r;
          if (rMin[r] < 2.f)  atomicMin(&minKey[row], fkey(rMin[r]));
          if (rMax[r] > -2.f) atomicMax(&maxKey[row], fkey(rMax[r]));
        }
      }
    }

    if (!diag) {
#pragma unroll
      for (int m = 16; m < 64; m <<= 1)
#pragma unroll
        for (int nt = 0; nt < 4; ++nt) {
          cMin[nt] = fminf(cMin[nt], __shfl_xor(cMin[nt], m, 64));
          cMax[nt] = fmaxf(cMax[nt], __shfl_xor(cMax[nt], m, 64));
        }
      if (lane < 16) {
#pragma unroll
        for (int nt = 0; nt < 4; ++nt) {
          const int col = bn + waveN * 64 + nt * 16 + fr;
          if (cMin[nt] < 2.f)  atomicMin(&minKey[col], fkey(cMin[nt]));
          if (cMax[nt] > -2.f) atomicMax(&maxKey[col], fkey(cMax[nt]));
        }
      }
    }
  }

  // ---- grid-wide barrier ----
  cg::this_grid().sync();

  // ---- phase 2: exp-sums from live acc registers ----
  if (tid < 128) {
    rMinp[tid] = funkey(minKey[bm + tid]);
    rMaxn[tid] = funkey(maxKey[bm + tid]);
  } else {
    cMinp[tid - 128] = funkey(minKey[bn + tid - 128]);
    cMaxn[tid - 128] = funkey(maxKey[bn + tid - 128]);
  }
  __syncthreads();

  float pCol[4] = {0.f, 0.f, 0.f, 0.f}, nCol[4] = {0.f, 0.f, 0.f, 0.f};

#pragma unroll
  for (int mt = 0; mt < 4; ++mt) {
    float pRow[4] = {0.f, 0.f, 0.f, 0.f}, nRow[4] = {0.f, 0.f, 0.f, 0.f};
    int labR[4]; float rmn[4], rmp[4];
#pragma unroll
    for (int r = 0; r < 4; ++r) {
      const int rl = waveM * 64 + mt * 16 + fq * 4 + r;
      labR[r] = rowLab[rl]; rmn[r] = rMaxn[rl]; rmp[r] = rMinp[rl];
    }
#pragma unroll
    for (int nt = 0; nt < 4; ++nt) {
      const int cl = waveN * 64 + nt * 16 + fr;
      const float cmn = cMaxn[cl], cmp = cMinp[cl];
#pragma unroll
      for (int r = 0; r < 4; ++r) {
        const int rl = waveM * 64 + mt * 16 + fq * 4 + r;
        const float s = acc[mt][nt][r];
        if (labR[r] == labC[nt]) {
          if (!(diag && rl == cl) && s < POS_CAP) {
            const float e = __expf(-SCALE_POS * (s - THRESH));
            if (s - MARGIN < rmn[r]) pRow[r] += e;
            if (s - MARGIN < cmn)    pCol[nt] += e;
          }
        } else {
          const float e = __expf(SCALE_NEG * (s - THRESH));
          if (s + MARGIN > rmp[r]) nRow[r] += e;
          if (s + MARGIN > cmp)    nCol[nt] += e;
        }
      }
    }
#pragma unroll
    for (int m = 1; m < 16; m <<= 1)
#pragma unroll
      for (int r = 0; r < 4; ++r) {
        pRow[r] += __shfl_xor(pRow[r], m, 64);
        nRow[r] += __shfl_xor(nRow[r], m, 64);
      }
    if (fr == 0) {
#pragma unroll
      for (int r = 0; r < 4; ++r) {
        const int row = bm + waveM * 64 + mt * 16 + fq * 4 + r;
        if (pRow[r] != 0.f) atomicAdd(&psum[row], pRow[r]);
        if (nRow[r] != 0.f) atomicAdd(&nsum[row], nRow[r]);
      }
    }
  }

  if (!diag) {
#pragma unroll
    for (int m = 16; m < 64; m <<= 1)
#pragma unroll
      for (int nt = 0; nt < 4; ++nt) {
        pCol[nt] += __shfl_xor(pCol[nt], m, 64);
        nCol[nt] += __shfl_xor(nCol[nt], m, 64);
      }
    if (lane < 16) {
#pragma unroll
      for (int nt = 0; nt < 4; ++nt) {
        const int col = bn + waveN * 64 + nt * 16 + fr;
        if (pCol[nt] != 0.f) atomicAdd(&psum[col], pCol[nt]);
        if (nCol[nt] != 0.f) atomicAdd(&nsum[col], nCol[nt]);
      }
    }
  }
}

// ===========================================================================
// Fallback path (R4, known-correct): GEMM+mine storing C, then exploss
// ===========================================================================
__global__ __launch_bounds__(256) void simgemm_mine_kernel(
    const uint16_t* __restrict__ X, const int* __restrict__ labels,
    float* __restrict__ C, unsigned* __restrict__ minKey,
    unsigned* __restrict__ maxKey, int B, int D, int NT) {
  __shared__ __align__(16) uint16_t sA[128 * 32];
  __shared__ __align__(16) uint16_t sB[128 * 32];
  __shared__ int rowLab[128];
  __shared__ int colLab[128];

  int rem = blockIdx.x;
  int bi = 0;
  while (rem >= NT - bi) { rem -= NT - bi; ++bi; }
  const int bj = bi + rem;
  const bool diag = (bi == bj);

  const int tid  = threadIdx.x;
  const int wave = tid >> 6;
  const int lane = tid & 63;
  const int waveM = wave >> 1, waveN = wave & 1;
  const int bm = bi * 128;
  const int bn = bj * 128;

  if (tid < 128) rowLab[tid] = labels[bm + tid];
  else           colLab[tid - 128] = labels[bn + tid - 128];

  const int r0 = tid >> 2,         c0 = (tid & 3) * 8;
  const int r1 = (tid + 256) >> 2, c1 = (tid & 3) * 8;

  const uint16_t* gA = X + (size_t)bm * D;
  const uint16_t* gB = X + (size_t)bn * D;

  uint16_t* lA0 = sA + wave * 512;
  uint16_t* lA1 = sA + 2048 + wave * 512;
  uint16_t* lB0 = sB + wave * 512;
  uint16_t* lB1 = sB + 2048 + wave * 512;

  const int fr = lane & 15;
  const int fq = lane >> 4;
  const int aoff = (waveM * 64 + fr) * 32 + fq * 8;
  const int boff = (waveN * 64 + fr) * 32 + fq * 8;

  const uint16_t* sBsrc = diag ? sA : sB;

  f32x4 acc[4][4] = {};

  for (int k0 = 0; k0 < D; k0 += 32) {
    stage16(gA + (size_t)r0 * D + k0 + c0, lA0, lane);
    stage16(gA + (size_t)r1 * D + k0 + c1, lA1, lane);
    if (!diag) {
      stage16(gB + (size_t)r0 * D + k0 + c0, lB0, lane);
      stage16(gB + (size_t)r1 * D + k0 + c1, lB1, lane);
    }
    __syncthreads();

    bf16x8 af[4], bfv[4];
#pragma unroll
    for (int t = 0; t < 4; ++t) af[t]  = *(const bf16x8*)(sA + aoff + t * 512);
#pragma unroll
    for (int t = 0; t < 4; ++t) bfv[t] = *(const bf16x8*)(sBsrc + boff + t * 512);

#pragma unroll
    for (int mt = 0; mt < 4; ++mt)
#pragma unroll
      for (int nt = 0; nt < 4; ++nt)
        acc[mt][nt] = __builtin_amdgcn_mfma_f32_16x16x32_bf16(
            af[mt], bfv[nt], acc[mt][nt], 0, 0, 0);
    __syncthreads();
  }

#pragma unroll
  for (int mt = 0; mt < 4; ++mt)
#pragma unroll
    for (int nt = 0; nt < 4; ++nt) {
      const int col = bn + waveN * 64 + nt * 16 + fr;
#pragma unroll
      for (int r = 0; r < 4; ++r) {
        const int row = bm + waveM * 64 + mt * 16 + fq * 4 + r;
        C[(size_t)row * B + col] = acc[mt][nt][r];
      }
    }

  int labC[4]; float cMin[4], cMax[4];
#pragma unroll
  for (int nt = 0; nt < 4; ++nt) {
    labC[nt] = colLab[waveN * 64 + nt * 16 + fr];
    cMin[nt] = 1e30f; cMax[nt] = -1e30f;
  }

#pragma unroll
  for (int mt = 0; mt < 4; ++mt) {
    float rMin[4], rMax[4]; int labR[4];
#pragma unroll
    for (int r = 0; r < 4; ++r) {
      labR[r] = rowLab[waveM * 64 + mt * 16 + fq * 4 + r];
      rMin[r] = 1e30f; rMax[r] = -1e30f;
    }
#pragma unroll
    for (int nt = 0; nt < 4; ++nt) {
      const int cl = waveN * 64 + nt * 16 + fr;
#pragma unroll
      for (int r = 0; r < 4; ++r) {
        const int rl = waveM * 64 + mt * 16 + fq * 4 + r;
        const float s = acc[mt][nt][r];
        if (labR[r] == labC[nt]) {
          if (!(diag && rl == cl) && s < POS_CAP) {
            rMin[r] = fminf(rMin[r], s);
            cMin[nt] = fminf(cMin[nt], s);
          }
        } else {
          rMax[r] = fmaxf(rMax[r], s);
          cMax[nt] = fmaxf(cMax[nt], s);
        }
      }
    }
#pragma unroll
    for (int m = 1; m < 16; m <<= 1)
#pragma unroll
      for (int r = 0; r < 4; ++r) {
        rMin[r] = fminf(rMin[r], __shfl_xor(rMin[r], m, 64));
        rMax[r] = fmaxf(rMax[r], __shfl_xor(rMax[r], m, 64));
      }
    if (fr == 0) {
#pragma unroll
      for (int r = 0; r < 4; ++r) {
        const int row = bm + waveM * 64 + mt * 16 + fq * 4 + r;
        if (rMin[r] < 2.f)  atomicMin(&minKey[row], fkey(rMin[r]));
        if (rMax[r] > -2.f) atomicMax(&maxKey[row], fkey(rMax[r]));
      }
    }
  }

  if (!diag) {
#pragma unroll
    for (int m = 16; m < 64; m <<= 1)
#pragma unroll
      for (int nt = 0; nt < 4; ++nt) {
        cMin[nt] = fminf(cMin[nt], __shfl_xor(cMin[nt], m, 64));
        cMax[nt] = fmaxf(cMax[nt], __shfl_xor(cMax[nt], m, 64));
      }
    if (lane < 16) {
#pragma unroll
      for (int nt = 0; nt < 4; ++nt) {
        const int col = bn + waveN * 64 + nt * 16 + fr;
        if (cMin[nt] < 2.f)  atomicMin(&minKey[col], fkey(cMin[nt]));
        if (cMax[nt] > -2.f) atomicMax(&maxKey[col], fkey(cMax[nt]));
      }
    }
  }
}

__global__ __launch_bounds__(256) void exploss_kernel(
    const float* __restrict__ C, const int* __restrict__ labels,
    const unsigned* __restrict__ minKey, const unsigned* __restrict__ maxKey,
    float* __restrict__ psum, float* __restrict__ nsum, int B, int NT) {
  __shared__ int   rLab[32];
  __shared__ float rMinp[32], rMaxn[32];
  __shared__ int   cLab[128];
  __shared__ float cMinp[128], cMaxn[128];
  __shared__ float pCarr[128], nCarr[128];

  int rem = blockIdx.x >> 2;
  const int split = blockIdx.x & 3;
  int bi = 0;
  while (rem >= NT - bi) { rem -= NT - bi; ++bi; }
  const int bj = bi + rem;
  const bool diag = (bi == bj);
  const int bm = bi * 128, bn = bj * 128;
  const int rbase = split * 32;

  const int tid = threadIdx.x;
  if (tid < 32) {
    const int row = bm + rbase + tid;
    rLab[tid]  = labels[row];
    rMinp[tid] = funkey(minKey[row]);
    rMaxn[tid] = funkey(maxKey[row]);
  } else if (tid < 160) {
    const int col = bn + (tid - 32);
    cLab[tid - 32]  = labels[col];
    cMinp[tid - 32] = funkey(minKey[col]);
    cMaxn[tid - 32] = funkey(maxKey[col]);
  }
  if (tid < 128) { pCarr[tid] = 0.f; nCarr[tid] = 0.f; }
  __syncthreads();

  const int rowg = tid >> 5;
  const int c0   = (tid & 31) * 4;
  int labC[4]; float mpC[4], mnC[4];
#pragma unroll
  for (int q = 0; q < 4; ++q) {
    labC[q] = cLab[c0 + q]; mpC[q] = cMinp[c0 + q]; mnC[q] = cMaxn[c0 + q];
  }
  float pCa[4] = {0.f, 0.f, 0.f, 0.f}, nCa[4] = {0.f, 0.f, 0.f, 0.f};

  for (int it = 0; it < 4; ++it) {
    const int rr = rowg + it * 8;
    const int rl = rbase + rr;
    const float4 v = *(const float4*)(C + (size_t)(bm + rl) * B + bn + c0);
    const float sq[4] = {v.x, v.y, v.z, v.w};
    const int   lr  = rLab[rr];
    const float rmn = rMaxn[rr];
    const float rmp = rMinp[rr];
    float pR = 0.f, nR = 0.f;
#pragma unroll
    for (int q = 0; q < 4; ++q) {
      const float s = sq[q];
      if (lr == labC[q]) {
        if (!(diag && rl == c0 + q) && s < POS_CAP) {
          const float e = __expf(-SCALE_POS * (s - THRESH));
          if (s - MARGIN < rmn)    pR += e;
          if (s - MARGIN < mnC[q]) pCa[q] += e;
        }
      } else {
        const float e = __expf(SCALE_NEG * (s - THRESH));
        if (s + MARGIN > rmp)    nR += e;
        if (s + MARGIN > mpC[q]) nCa[q] += e;
      }
    }
#pragma unroll
    for (int m = 1; m < 32; m <<= 1) {
      pR += __shfl_xor(pR, m, 64);
      nR += __shfl_xor(nR, m, 64);
    }
    if ((tid & 31) == 0) {
      atomicAdd(&psum[bm + rl], pR);
      atomicAdd(&nsum[bm + rl], nR);
    }
  }

  if (!diag) {
#pragma unroll
    for (int q = 0; q < 4; ++q) {
      atomicAdd(&pCarr[c0 + q], pCa[q]);
      atomicAdd(&nCarr[c0 + q], nCa[q]);
    }
    __syncthreads();
    if (tid < 128) {
      if (pCarr[tid] != 0.f) atomicAdd(&psum[bn + tid], pCarr[tid]);
      if (nCarr[tid] != 0.f) atomicAdd(&nsum[bn + tid], nCarr[tid]);
    }
  }
}

// ---- final: per-row loss + total -------------------------------------------
__global__ __launch_bounds__(1024) void final_kernel(
    const unsigned* __restrict__ minKey, const unsigned* __restrict__ maxKey,
    const float* __restrict__ psum, const float* __restrict__ nsum,
    float* __restrict__ out, int B) {
  __shared__ float red[16];
  const int tid = threadIdx.x;
  float acc = 0.f;
  for (int i = tid; i < B; i += 1024) {
    const unsigned mk = minKey[i], xk = maxKey[i];
    const float p = psum[i], n = nsum[i];
    if (mk != 0xFFFFFFFFu && xk != 0u && p > 0.f && n > 0.f)
      acc += log1pf(p) * (1.0f / SCALE_POS) + log1pf(n) * (1.0f / SCALE_NEG);
  }
#pragma unroll
  for (int m = 32; m > 0; m >>= 1) acc += __shfl_xor(acc, m, 64);
  if ((tid & 63) == 0) red[tid >> 6] = acc;
  __syncthreads();
  if (tid == 0) {
    float t = 0.f;
#pragma unroll
    for (int w = 0; w < 16; ++w) t += red[w];
    out[0] = t / (float)B;
  }
}

// ---------------------------------------------------------------------------
extern "C" void kernel_launch(void* const* d_in, const int* in_sizes, int n_in,
                              void* d_out, int out_size, void* d_ws, size_t ws_size,
                              hipStream_t stream) {
  const float* x      = (const float*)d_in[0];
  const int*   labels = (const int*)d_in[1];
  float*       out    = (float*)d_out;

  int B = in_sizes[1];            // 4096
  int D = in_sizes[0] / B;        // 1024
  int NT = B / 128;               // 32
  const int NTILES = NT * (NT + 1) / 2;  // 528

  uint16_t* xbf = (uint16_t*)d_ws;
  size_t xbytes = (((size_t)B * D * 2) + 255) & ~(size_t)255;
  unsigned* minKey = (unsigned*)((char*)d_ws + xbytes);
  unsigned* maxKey = minKey + B;
  float* psumA = (float*)(maxKey + B);
  float* nsumA = psumA + B;
  float* sim   = (float*)((char*)d_ws + xbytes + ((size_t)B * 16 + 255 & ~(size_t)255));

  hipMemsetAsync(minKey, 0xFF, (size_t)B * 4, stream);
  hipMemsetAsync(maxKey, 0x00, (size_t)B * 12, stream);  // maxKey+psum+nsum

  const int n = B * D;
  cvt_bf16_kernel<<<n / 1024, 256, 0, stream>>>(x, xbf, n);

  // Host-side occupancy check (deterministic; graph-capture-safe: no stream op).
  int perMP = 0;
  hipOccupancyMaxActiveBlocksPerMultiprocessor(&perMP, fused_kernel, 256, 0);
  int numMP = 0;
  hipDeviceGetAttribute(&numMP, hipDeviceAttributeMultiprocessorCount, 0);
  const bool coop_ok = (perMP > 0 && numMP > 0 && (long)perMP * numMP >= NTILES);

  if (coop_ok) {
    void* args[] = {(void*)&xbf, (void*)&labels, (void*)&minKey, (void*)&maxKey,
                    (void*)&psumA, (void*)&nsumA, (void*)&B, (void*)&D, (void*)&NT};
    hipLaunchCooperativeKernel((void*)fused_kernel, dim3(NTILES), dim3(256),
                               args, 0, stream);
  } else {
    simgemm_mine_kernel<<<NTILES, 256, 0, stream>>>(xbf, labels, sim, minKey, maxKey, B, D, NT);
    exploss_kernel<<<NTILES * 4, 256, 0, stream>>>(sim, labels, minKey, maxKey, psumA, nsumA, B, NT);
  }

  final_kernel<<<1, 1024, 0, stream>>>(minKey, maxKey, psumA, nsumA, out, B);
}

// Round 7
// 147.607 us; speedup vs baseline: 1.0326x; 1.0241x over previous
//
#include <hip/hip_runtime.h>
#include <hip/hip_bf16.h>
#include <hip/hip_cooperative_groups.h>
#include <math.h>
#include <stdint.h>

namespace cg = cooperative_groups;

// ---------------------------------------------------------------------------
// MultiSimilarityLoss on MI355X (gfx950).
//   x: [B=4096, D=1024] fp32 (L2-normalized), labels: [B] int32 -> scalar loss
//
// R7: fused cooperative pipeline, restructured for cooperative residency.
// R6 post-mortem: 128x128 tiles -> 528 blocks -> 2.06 blocks/CU co-resident,
//   16 CUs got a 3rd block -> makespan 1.5x, spills (7.7MB scratch) across
//   grid.sync, MfmaUtil 6.5%. Fixes:
//   - 128x64 half-tiles -> 1056 blocks (4.125/CU, imbalance 1.21x), acc=32
//     regs (no spill), launch_bounds(256,5) -> 5 blocks/CU capacity 1280.
//   - 2 graph nodes only: cvt+init, then coop kernel with TWO grid.sync()s
//     (mine -> sync -> exp-sums -> sync -> block0 final reduce). ~10us/node
//     overhead observed across rounds makes node count expensive.
// ---------------------------------------------------------------------------

#define THRESH    0.5f
#define MARGIN    0.1f
#define SCALE_POS 2.0f
#define SCALE_NEG 40.0f
#define POS_CAP   (1.0f - 1e-5f)

typedef __bf16 bf16x8 __attribute__((ext_vector_type(8)));
typedef float  f32x4  __attribute__((ext_vector_type(4)));

// ---- fp32 -> bf16 (RNE) ----------------------------------------------------
__device__ __forceinline__ uint16_t f2bf(float f) {
  union { float f; uint32_t u; } v; v.f = f;
  uint32_t u = v.u;
  u += 0x7FFFu + ((u >> 16) & 1u);
  return (uint16_t)(u >> 16);
}

// cvt + workspace init fused (kills 2 memset graph nodes)
__global__ __launch_bounds__(256) void cvt_init_kernel(
    const float* __restrict__ x, uint16_t* __restrict__ y, int n,
    unsigned* __restrict__ minKey, unsigned* __restrict__ maxKey,
    float* __restrict__ psum, float* __restrict__ nsum, int B) {
  int i = (blockIdx.x * 256 + threadIdx.x) * 4;
  if (i + 3 < n) {
    float4 v = *(const float4*)(x + i);
    ushort4 o;
    o.x = f2bf(v.x); o.y = f2bf(v.y); o.z = f2bf(v.z); o.w = f2bf(v.w);
    *(ushort4*)(y + i) = o;
  }
  const int nb = (B + 127) / 128;
  if (blockIdx.x < (unsigned)nb && threadIdx.x < 128) {
    const int j = blockIdx.x * 128 + threadIdx.x;
    if (j < B) {
      minKey[j] = 0xFFFFFFFFu;  // decodes to NaN ("no positive found")
      maxKey[j] = 0u;           // decodes to NaN ("no negative found")
      psum[j] = 0.f; nsum[j] = 0.f;
    }
  }
}

// ---- monotone float <-> uint key (atomicMin/Max on floats) -----------------
__device__ __forceinline__ unsigned fkey(float f) {
  unsigned u = __float_as_uint(f);
  return (u & 0x80000000u) ? ~u : (u | 0x80000000u);
}
__device__ __forceinline__ float funkey(unsigned k) {
  unsigned u = (k & 0x80000000u) ? (k & 0x7FFFFFFFu) : ~k;
  return __uint_as_float(u);
}

// ---- async global->LDS staging (16B / lane) --------------------------------
#if defined(__has_builtin)
#if __has_builtin(__builtin_amdgcn_global_load_lds)
#define HAVE_GLL 1
#endif
#endif

__device__ __forceinline__ void stage16(const uint16_t* g, uint16_t* lds_wave_base, int lane) {
#ifdef HAVE_GLL
  __builtin_amdgcn_global_load_lds(
      (const __attribute__((address_space(1))) void*)g,
      (__attribute__((address_space(3))) void*)lds_wave_base, 16, 0, 0);
#else
  *(uint4*)(lds_wave_base + lane * 8) = *(const uint4*)g;
#endif
}

// ===========================================================================
// R7 coop kernel: 128x64 half-tile GEMM + mine + sync + exp-loss + sync + final
// Grid = NT*(NT+1) blocks (1056 for B=4096):
//   h <  NT*(NT-1): off-diag half; supertile s=h>>1 (bi<bj), side=h&1
//   h >= NT*(NT-1): diag half; d=h-NT*(NT-1); bi=bj=d>>1, side=d&1
// Block covers rows [bi*128,+128) x cols [bj*128+side*64,+64).
// Diag halves: both orders of each pair appear across the 2 halves -> row-side
// only. Off-diag: row-side + col-side (mirror).
// ===========================================================================
__global__ __launch_bounds__(256, 5) void fused_kernel(
    const uint16_t* __restrict__ X, const int* __restrict__ labels,
    unsigned* __restrict__ minKey, unsigned* __restrict__ maxKey,
    float* __restrict__ psum, float* __restrict__ nsum,
    float* __restrict__ out, int B, int D, int NT) {
  __shared__ __align__(16) uint16_t sA[128 * 32];  // 8 KB: A panel 128 rows
  __shared__ __align__(16) uint16_t sB[64 * 32];   // 4 KB: B half  64 cols
  __shared__ int   rowLab[128], colLab[64];
  __shared__ float rMinp[128], rMaxn[128], cMinp[64], cMaxn[64];
  __shared__ float red[8];

  const int h = blockIdx.x;
  const int offc = NT * (NT - 1);  // off-diag half count (992)
  int bi, bj, side;
  if (h < offc) {
    const int s = h >> 1; side = h & 1;
    int rem = s; bi = 0;
    while (rem >= NT - 1 - bi) { rem -= NT - 1 - bi; ++bi; }
    bj = bi + 1 + rem;
  } else {
    const int d = h - offc; bi = bj = d >> 1; side = d & 1;
  }
  const bool diag = (bi == bj);

  const int tid  = threadIdx.x;
  const int wave = tid >> 6;
  const int lane = tid & 63;
  const int waveM = wave >> 1, waveN = wave & 1;  // 2x2 waves over 128x64
  const int bm  = bi * 128;
  const int bnc = bj * 128 + side * 64;  // global col base (64 cols)

  if (tid < 128)      rowLab[tid] = labels[bm + tid];
  else if (tid < 192) colLab[tid - 128] = labels[bnc + (tid - 128)];

  // staging: sA = 512 chunks of 16B (2/thread), sB = 256 chunks (1/thread)
  const int rA0 = tid >> 2,         cA = (tid & 3) * 8;
  const int rA1 = (tid + 256) >> 2;
  const int rB0 = tid >> 2;

  const uint16_t* gA = X + (size_t)bm * D;
  const uint16_t* gB = X + (size_t)bnc * D;

  uint16_t* lA0 = sA + wave * 512;
  uint16_t* lA1 = sA + 2048 + wave * 512;
  uint16_t* lB0 = sB + wave * 512;

  const int fr = lane & 15;
  const int fq = lane >> 4;
  const int aoff = (waveM * 64 + fr) * 32 + fq * 8;
  // B fragment: off-diag reads sB; diag reads the matching rows of sA
  const uint16_t* bsrc = diag ? sA : sB;
  const int boff = diag ? ((side * 64 + waveN * 32 + fr) * 32 + fq * 8)
                        : ((waveN * 32 + fr) * 32 + fq * 8);

  f32x4 acc[4][2] = {};

  for (int k0 = 0; k0 < D; k0 += 32) {
    stage16(gA + (size_t)rA0 * D + k0 + cA, lA0, lane);
    stage16(gA + (size_t)rA1 * D + k0 + cA, lA1, lane);
    if (!diag) stage16(gB + (size_t)rB0 * D + k0 + cA, lB0, lane);
    __syncthreads();

    bf16x8 af[4], bfv[2];
#pragma unroll
    for (int t = 0; t < 4; ++t) af[t] = *(const bf16x8*)(sA + aoff + t * 512);
#pragma unroll
    for (int t = 0; t < 2; ++t) bfv[t] = *(const bf16x8*)(bsrc + boff + t * 512);

#pragma unroll
    for (int mt = 0; mt < 4; ++mt)
#pragma unroll
      for (int nt = 0; nt < 2; ++nt)
        acc[mt][nt] = __builtin_amdgcn_mfma_f32_16x16x32_bf16(
            af[mt], bfv[nt], acc[mt][nt], 0, 0, 0);
    __syncthreads();
  }

  // ---- phase 1: mine per-row (always) + per-col (off-diag) min/max ----
  int labC[2];
#pragma unroll
  for (int nt = 0; nt < 2; ++nt) labC[nt] = colLab[waveN * 32 + nt * 16 + fr];

  {
    float cMin[2] = {1e30f, 1e30f}, cMax[2] = {-1e30f, -1e30f};

#pragma unroll
    for (int mt = 0; mt < 4; ++mt) {
      float rMin[4], rMax[4]; int labR[4];
#pragma unroll
      for (int r = 0; r < 4; ++r) {
        labR[r] = rowLab[waveM * 64 + mt * 16 + fq * 4 + r];
        rMin[r] = 1e30f; rMax[r] = -1e30f;
      }
#pragma unroll
      for (int nt = 0; nt < 2; ++nt) {
        const int cl = waveN * 32 + nt * 16 + fr;
#pragma unroll
        for (int r = 0; r < 4; ++r) {
          const int rl = waveM * 64 + mt * 16 + fq * 4 + r;
          const float s = acc[mt][nt][r];
          if (labR[r] == labC[nt]) {
            if (!(diag && rl == side * 64 + cl) && s < POS_CAP) {
              rMin[r] = fminf(rMin[r], s);
              cMin[nt] = fminf(cMin[nt], s);
            }
          } else {
            rMax[r] = fmaxf(rMax[r], s);
            cMax[nt] = fmaxf(cMax[nt], s);
          }
        }
      }
#pragma unroll
      for (int m = 1; m < 16; m <<= 1)
#pragma unroll
        for (int r = 0; r < 4; ++r) {
          rMin[r] = fminf(rMin[r], __shfl_xor(rMin[r], m, 64));
          rMax[r] = fmaxf(rMax[r], __shfl_xor(rMax[r], m, 64));
        }
      if (fr == 0) {
#pragma unroll
        for (int r = 0; r < 4; ++r) {
          const int row = bm + waveM * 64 + mt * 16 + fq * 4 + r;
          if (rMin[r] < 2.f)  atomicMin(&minKey[row], fkey(rMin[r]));
          if (rMax[r] > -2.f) atomicMax(&maxKey[row], fkey(rMax[r]));
        }
      }
    }

    if (!diag) {
#pragma unroll
      for (int m = 16; m < 64; m <<= 1)
#pragma unroll
        for (int nt = 0; nt < 2; ++nt) {
          cMin[nt] = fminf(cMin[nt], __shfl_xor(cMin[nt], m, 64));
          cMax[nt] = fmaxf(cMax[nt], __shfl_xor(cMax[nt], m, 64));
        }
      if (lane < 16) {
#pragma unroll
        for (int nt = 0; nt < 2; ++nt) {
          const int col = bnc + waveN * 32 + nt * 16 + fr;
          if (cMin[nt] < 2.f)  atomicMin(&minKey[col], fkey(cMin[nt]));
          if (cMax[nt] > -2.f) atomicMax(&maxKey[col], fkey(cMax[nt]));
        }
      }
    }
  }

  // ---- grid barrier #1: min/max now global ----
  cg::this_grid().sync();

  if (tid < 128) {
    rMinp[tid] = funkey(minKey[bm + tid]);
    rMaxn[tid] = funkey(maxKey[bm + tid]);
  } else if (tid < 192) {
    cMinp[tid - 128] = funkey(minKey[bnc + (tid - 128)]);
    cMaxn[tid - 128] = funkey(maxKey[bnc + (tid - 128)]);
  }
  __syncthreads();

  // ---- phase 2: exp-sums from live acc registers ----
  {
    float pCol[2] = {0.f, 0.f}, nCol[2] = {0.f, 0.f};

#pragma unroll
    for (int mt = 0; mt < 4; ++mt) {
      float pRow[4] = {0.f, 0.f, 0.f, 0.f}, nRow[4] = {0.f, 0.f, 0.f, 0.f};
      int labR[4]; float rmn[4], rmp[4];
#pragma unroll
      for (int r = 0; r < 4; ++r) {
        const int rl = waveM * 64 + mt * 16 + fq * 4 + r;
        labR[r] = rowLab[rl]; rmn[r] = rMaxn[rl]; rmp[r] = rMinp[rl];
      }
#pragma unroll
      for (int nt = 0; nt < 2; ++nt) {
        const int cl = waveN * 32 + nt * 16 + fr;
        const float cmn = cMaxn[cl], cmp = cMinp[cl];
#pragma unroll
        for (int r = 0; r < 4; ++r) {
          const int rl = waveM * 64 + mt * 16 + fq * 4 + r;
          const float s = acc[mt][nt][r];
          if (labR[r] == labC[nt]) {
            if (!(diag && rl == side * 64 + cl) && s < POS_CAP) {
              const float e = __expf(-SCALE_POS * (s - THRESH));
              if (s - MARGIN < rmn[r]) pRow[r] += e;
              if (!diag && s - MARGIN < cmn) pCol[nt] += e;
            }
          } else {
            const float e = __expf(SCALE_NEG * (s - THRESH));
            if (s + MARGIN > rmp[r]) nRow[r] += e;
            if (!diag && s + MARGIN > cmp) nCol[nt] += e;
          }
        }
      }
#pragma unroll
      for (int m = 1; m < 16; m <<= 1)
#pragma unroll
        for (int r = 0; r < 4; ++r) {
          pRow[r] += __shfl_xor(pRow[r], m, 64);
          nRow[r] += __shfl_xor(nRow[r], m, 64);
        }
      if (fr == 0) {
#pragma unroll
        for (int r = 0; r < 4; ++r) {
          const int row = bm + waveM * 64 + mt * 16 + fq * 4 + r;
          if (pRow[r] != 0.f) atomicAdd(&psum[row], pRow[r]);
          if (nRow[r] != 0.f) atomicAdd(&nsum[row], nRow[r]);
        }
      }
    }

    if (!diag) {
#pragma unroll
      for (int m = 16; m < 64; m <<= 1)
#pragma unroll
        for (int nt = 0; nt < 2; ++nt) {
          pCol[nt] += __shfl_xor(pCol[nt], m, 64);
          nCol[nt] += __shfl_xor(nCol[nt], m, 64);
        }
      if (lane < 16) {
#pragma unroll
        for (int nt = 0; nt < 2; ++nt) {
          const int col = bnc + waveN * 32 + nt * 16 + fr;
          if (pCol[nt] != 0.f) atomicAdd(&psum[col], pCol[nt]);
          if (nCol[nt] != 0.f) atomicAdd(&nsum[col], nCol[nt]);
        }
      }
    }
  }

  // ---- grid barrier #2: psum/nsum complete; block 0 finalizes ----
  cg::this_grid().sync();

  if (blockIdx.x == 0) {
    float accl = 0.f;
    for (int i = tid; i < B; i += 256) {
      const unsigned mk = minKey[i], xk = maxKey[i];
      const float p = psum[i], n = nsum[i];
      if (mk != 0xFFFFFFFFu && xk != 0u && p > 0.f && n > 0.f)
        accl += log1pf(p) * (1.0f / SCALE_POS) + log1pf(n) * (1.0f / SCALE_NEG);
    }
#pragma unroll
    for (int m = 32; m > 0; m >>= 1) accl += __shfl_xor(accl, m, 64);
    if (lane == 0) red[wave] = accl;
    __syncthreads();
    if (tid == 0)
      out[0] = (red[0] + red[1] + red[2] + red[3]) / (float)B;
  }
}

// ===========================================================================
// Fallback path (R4, known-correct): GEMM+mine storing C, exploss, final
// ===========================================================================
__global__ __launch_bounds__(256) void simgemm_mine_kernel(
    const uint16_t* __restrict__ X, const int* __restrict__ labels,
    float* __restrict__ C, unsigned* __restrict__ minKey,
    unsigned* __restrict__ maxKey, int B, int D, int NT) {
  __shared__ __align__(16) uint16_t sA[128 * 32];
  __shared__ __align__(16) uint16_t sB[128 * 32];
  __shared__ int rowLab[128];
  __shared__ int colLab[128];

  int rem = blockIdx.x;
  int bi = 0;
  while (rem >= NT - bi) { rem -= NT - bi; ++bi; }
  const int bj = bi + rem;
  const bool diag = (bi == bj);

  const int tid  = threadIdx.x;
  const int wave = tid >> 6;
  const int lane = tid & 63;
  const int waveM = wave >> 1, waveN = wave & 1;
  const int bm = bi * 128;
  const int bn = bj * 128;

  if (tid < 128) rowLab[tid] = labels[bm + tid];
  else           colLab[tid - 128] = labels[bn + tid - 128];

  const int r0 = tid >> 2,         c0 = (tid & 3) * 8;
  const int r1 = (tid + 256) >> 2, c1 = (tid & 3) * 8;

  const uint16_t* gA = X + (size_t)bm * D;
  const uint16_t* gB = X + (size_t)bn * D;

  uint16_t* lA0 = sA + wave * 512;
  uint16_t* lA1 = sA + 2048 + wave * 512;
  uint16_t* lB0 = sB + wave * 512;
  uint16_t* lB1 = sB + 2048 + wave * 512;

  const int fr = lane & 15;
  const int fq = lane >> 4;
  const int aoff = (waveM * 64 + fr) * 32 + fq * 8;
  const int boff = (waveN * 64 + fr) * 32 + fq * 8;

  const uint16_t* sBsrc = diag ? sA : sB;

  f32x4 acc[4][4] = {};

  for (int k0 = 0; k0 < D; k0 += 32) {
    stage16(gA + (size_t)r0 * D + k0 + c0, lA0, lane);
    stage16(gA + (size_t)r1 * D + k0 + c1, lA1, lane);
    if (!diag) {
      stage16(gB + (size_t)r0 * D + k0 + c0, lB0, lane);
      stage16(gB + (size_t)r1 * D + k0 + c1, lB1, lane);
    }
    __syncthreads();

    bf16x8 af[4], bfv[4];
#pragma unroll
    for (int t = 0; t < 4; ++t) af[t]  = *(const bf16x8*)(sA + aoff + t * 512);
#pragma unroll
    for (int t = 0; t < 4; ++t) bfv[t] = *(const bf16x8*)(sBsrc + boff + t * 512);

#pragma unroll
    for (int mt = 0; mt < 4; ++mt)
#pragma unroll
      for (int nt = 0; nt < 4; ++nt)
        acc[mt][nt] = __builtin_amdgcn_mfma_f32_16x16x32_bf16(
            af[mt], bfv[nt], acc[mt][nt], 0, 0, 0);
    __syncthreads();
  }

#pragma unroll
  for (int mt = 0; mt < 4; ++mt)
#pragma unroll
    for (int nt = 0; nt < 4; ++nt) {
      const int col = bn + waveN * 64 + nt * 16 + fr;
#pragma unroll
      for (int r = 0; r < 4; ++r) {
        const int row = bm + waveM * 64 + mt * 16 + fq * 4 + r;
        C[(size_t)row * B + col] = acc[mt][nt][r];
      }
    }

  int labC[4]; float cMin[4], cMax[4];
#pragma unroll
  for (int nt = 0; nt < 4; ++nt) {
    labC[nt] = colLab[waveN * 64 + nt * 16 + fr];
    cMin[nt] = 1e30f; cMax[nt] = -1e30f;
  }

#pragma unroll
  for (int mt = 0; mt < 4; ++mt) {
    float rMin[4], rMax[4]; int labR[4];
#pragma unroll
    for (int r = 0; r < 4; ++r) {
      labR[r] = rowLab[waveM * 64 + mt * 16 + fq * 4 + r];
      rMin[r] = 1e30f; rMax[r] = -1e30f;
    }
#pragma unroll
    for (int nt = 0; nt < 4; ++nt) {
      const int cl = waveN * 64 + nt * 16 + fr;
#pragma unroll
      for (int r = 0; r < 4; ++r) {
        const int rl = waveM * 64 + mt * 16 + fq * 4 + r;
        const float s = acc[mt][nt][r];
        if (labR[r] == labC[nt]) {
          if (!(diag && rl == cl) && s < POS_CAP) {
            rMin[r] = fminf(rMin[r], s);
            cMin[nt] = fminf(cMin[nt], s);
          }
        } else {
          rMax[r] = fmaxf(rMax[r], s);
          cMax[nt] = fmaxf(cMax[nt], s);
        }
      }
    }
#pragma unroll
    for (int m = 1; m < 16; m <<= 1)
#pragma unroll
      for (int r = 0; r < 4; ++r) {
        rMin[r] = fminf(rMin[r], __shfl_xor(rMin[r], m, 64));
        rMax[r] = fmaxf(rMax[r], __shfl_xor(rMax[r], m, 64));
      }
    if (fr == 0) {
#pragma unroll
      for (int r = 0; r < 4; ++r) {
        const int row = bm + waveM * 64 + mt * 16 + fq * 4 + r;
        if (rMin[r] < 2.f)  atomicMin(&minKey[row], fkey(rMin[r]));
        if (rMax[r] > -2.f) atomicMax(&maxKey[row], fkey(rMax[r]));
      }
    }
  }

  if (!diag) {
#pragma unroll
    for (int m = 16; m < 64; m <<= 1)
#pragma unroll
      for (int nt = 0; nt < 4; ++nt) {
        cMin[nt] = fminf(cMin[nt], __shfl_xor(cMin[nt], m, 64));
        cMax[nt] = fmaxf(cMax[nt], __shfl_xor(cMax[nt], m, 64));
      }
    if (lane < 16) {
#pragma unroll
      for (int nt = 0; nt < 4; ++nt) {
        const int col = bn + waveN * 64 + nt * 16 + fr;
        if (cMin[nt] < 2.f)  atomicMin(&minKey[col], fkey(cMin[nt]));
        if (cMax[nt] > -2.f) atomicMax(&maxKey[col], fkey(cMax[nt]));
      }
    }
  }
}

__global__ __launch_bounds__(256) void exploss_kernel(
    const float* __restrict__ C, const int* __restrict__ labels,
    const unsigned* __restrict__ minKey, const unsigned* __restrict__ maxKey,
    float* __restrict__ psum, float* __restrict__ nsum, int B, int NT) {
  __shared__ int   rLab[32];
  __shared__ float rMinp[32], rMaxn[32];
  __shared__ int   cLab[128];
  __shared__ float cMinp[128], cMaxn[128];
  __shared__ float pCarr[128], nCarr[128];

  int rem = blockIdx.x >> 2;
  const int split = blockIdx.x & 3;
  int bi = 0;
  while (rem >= NT - bi) { rem -= NT - bi; ++bi; }
  const int bj = bi + rem;
  const bool diag = (bi == bj);
  const int bm = bi * 128, bn = bj * 128;
  const int rbase = split * 32;

  const int tid = threadIdx.x;
  if (tid < 32) {
    const int row = bm + rbase + tid;
    rLab[tid]  = labels[row];
    rMinp[tid] = funkey(minKey[row]);
    rMaxn[tid] = funkey(maxKey[row]);
  } else if (tid < 160) {
    const int col = bn + (tid - 32);
    cLab[tid - 32]  = labels[col];
    cMinp[tid - 32] = funkey(minKey[col]);
    cMaxn[tid - 32] = funkey(maxKey[col]);
  }
  if (tid < 128) { pCarr[tid] = 0.f; nCarr[tid] = 0.f; }
  __syncthreads();

  const int rowg = tid >> 5;
  const int c0   = (tid & 31) * 4;
  int labC[4]; float mpC[4], mnC[4];
#pragma unroll
  for (int q = 0; q < 4; ++q) {
    labC[q] = cLab[c0 + q]; mpC[q] = cMinp[c0 + q]; mnC[q] = cMaxn[c0 + q];
  }
  float pCa[4] = {0.f, 0.f, 0.f, 0.f}, nCa[4] = {0.f, 0.f, 0.f, 0.f};

  for (int it = 0; it < 4; ++it) {
    const int rr = rowg + it * 8;
    const int rl = rbase + rr;
    const float4 v = *(const float4*)(C + (size_t)(bm + rl) * B + bn + c0);
    const float sq[4] = {v.x, v.y, v.z, v.w};
    const int   lr  = rLab[rr];
    const float rmn = rMaxn[rr];
    const float rmp = rMinp[rr];
    float pR = 0.f, nR = 0.f;
#pragma unroll
    for (int q = 0; q < 4; ++q) {
      const float s = sq[q];
      if (lr == labC[q]) {
        if (!(diag && rl == c0 + q) && s < POS_CAP) {
          const float e = __expf(-SCALE_POS * (s - THRESH));
          if (s - MARGIN < rmn)    pR += e;
          if (s - MARGIN < mnC[q]) pCa[q] += e;
        }
      } else {
        const float e = __expf(SCALE_NEG * (s - THRESH));
        if (s + MARGIN > rmp)    nR += e;
        if (s + MARGIN > mpC[q]) nCa[q] += e;
      }
    }
#pragma unroll
    for (int m = 1; m < 32; m <<= 1) {
      pR += __shfl_xor(pR, m, 64);
      nR += __shfl_xor(nR, m, 64);
    }
    if ((tid & 31) == 0) {
      atomicAdd(&psum[bm + rl], pR);
      atomicAdd(&nsum[bm + rl], nR);
    }
  }

  if (!diag) {
#pragma unroll
    for (int q = 0; q < 4; ++q) {
      atomicAdd(&pCarr[c0 + q], pCa[q]);
      atomicAdd(&nCarr[c0 + q], nCa[q]);
    }
    __syncthreads();
    if (tid < 128) {
      if (pCarr[tid] != 0.f) atomicAdd(&psum[bn + tid], pCarr[tid]);
      if (nCarr[tid] != 0.f) atomicAdd(&nsum[bn + tid], nCarr[tid]);
    }
  }
}

__global__ __launch_bounds__(1024) void final_kernel(
    const unsigned* __restrict__ minKey, const unsigned* __restrict__ maxKey,
    const float* __restrict__ psum, const float* __restrict__ nsum,
    float* __restrict__ out, int B) {
  __shared__ float red[16];
  const int tid = threadIdx.x;
  float acc = 0.f;
  for (int i = tid; i < B; i += 1024) {
    const unsigned mk = minKey[i], xk = maxKey[i];
    const float p = psum[i], n = nsum[i];
    if (mk != 0xFFFFFFFFu && xk != 0u && p > 0.f && n > 0.f)
      acc += log1pf(p) * (1.0f / SCALE_POS) + log1pf(n) * (1.0f / SCALE_NEG);
  }
#pragma unroll
  for (int m = 32; m > 0; m >>= 1) acc += __shfl_xor(acc, m, 64);
  if ((tid & 63) == 0) red[tid >> 6] = acc;
  __syncthreads();
  if (tid == 0) {
    float t = 0.f;
#pragma unroll
    for (int w = 0; w < 16; ++w) t += red[w];
    out[0] = t / (float)B;
  }
}

// ---------------------------------------------------------------------------
extern "C" void kernel_launch(void* const* d_in, const int* in_sizes, int n_in,
                              void* d_out, int out_size, void* d_ws, size_t ws_size,
                              hipStream_t stream) {
  const float* x      = (const float*)d_in[0];
  const int*   labels = (const int*)d_in[1];
  float*       out    = (float*)d_out;

  int B = in_sizes[1];            // 4096
  int D = in_sizes[0] / B;        // 1024
  int NT = B / 128;               // 32
  const int NHALF  = NT * (NT + 1);      // 1056 half-tiles (coop grid)
  const int NTILES = NT * (NT + 1) / 2;  // 528 full tiles (fallback grid)

  uint16_t* xbf = (uint16_t*)d_ws;
  size_t xbytes = (((size_t)B * D * 2) + 255) & ~(size_t)255;
  unsigned* minKey = (unsigned*)((char*)d_ws + xbytes);
  unsigned* maxKey = minKey + B;
  float* psumA = (float*)(maxKey + B);
  float* nsumA = psumA + B;
  float* sim   = (float*)((char*)d_ws + xbytes + (((size_t)B * 16 + 255) & ~(size_t)255));

  const int n = B * D;
  cvt_init_kernel<<<n / 1024, 256, 0, stream>>>(x, xbf, n, minKey, maxKey,
                                                psumA, nsumA, B);

  // Host-side occupancy check (host query only; graph-capture-safe).
  int perMP = 0;
  hipOccupancyMaxActiveBlocksPerMultiprocessor(&perMP, fused_kernel, 256, 0);
  int numMP = 0;
  hipDeviceGetAttribute(&numMP, hipDeviceAttributeMultiprocessorCount, 0);
  const bool coop_ok = (perMP > 0 && numMP > 0 && (long)perMP * numMP >= NHALF);

  if (coop_ok) {
    void* args[] = {(void*)&xbf, (void*)&labels, (void*)&minKey, (void*)&maxKey,
                    (void*)&psumA, (void*)&nsumA, (void*)&out,
                    (void*)&B, (void*)&D, (void*)&NT};
    hipLaunchCooperativeKernel((void*)fused_kernel, dim3(NHALF), dim3(256),
                               args, 0, stream);
  } else {
    simgemm_mine_kernel<<<NTILES, 256, 0, stream>>>(xbf, labels, sim, minKey, maxKey, B, D, NT);
    exploss_kernel<<<NTILES * 4, 256, 0, stream>>>(sim, labels, minKey, maxKey, psumA, nsumA, B, NT);
    final_kernel<<<1, 1024, 0, stream>>>(minKey, maxKey, psumA, nsumA, out, B);
  }
}